// Round 6
// baseline (312.642 us; speedup 1.0000x reference)
//
#include <hip/hip_runtime.h>
#include <stdint.h>

typedef unsigned short u16;
typedef unsigned int u32;
typedef short s16x8 __attribute__((ext_vector_type(8)));
typedef float f32x4 __attribute__((ext_vector_type(4)));
typedef float f32x16 __attribute__((ext_vector_type(16)));
typedef u32 u32x2 __attribute__((ext_vector_type(2)));

#define DIM 256
#define HW  4096
#define NB  8
#define QSCL 0.18033688011112042f   // 0.125 * log2(e): softmax scale + log2-domain folded into Q

template <int N> struct ic { static constexpr int value = N; };

__device__ __forceinline__ u16 f2bf(float f) {
  union { float f; unsigned u; } v; v.f = f;
  unsigned r = v.u + 0x7FFFu + ((v.u >> 16) & 1u);
  return (u16)(r >> 16);
}
__device__ __forceinline__ float fexp2(float x) { return __builtin_amdgcn_exp2f(x); }
__device__ __forceinline__ u32 cvtpk(float a, float b) {
  u32 r; asm("v_cvt_pk_bf16_f32 %0, %1, %2" : "=v"(r) : "v"(a), "v"(b)); return r;
}

typedef __attribute__((address_space(1))) const void gvoid_c;
typedef __attribute__((address_space(3))) void lvoid;
__device__ __forceinline__ void gload_lds16(const void* g, void* l) {
  __builtin_amdgcn_global_load_lds((gvoid_c*)g, (lvoid*)l, 16, 0, 0);
}
__device__ __forceinline__ f32x16 mfma32(s16x8 a, s16x8 b, f32x16 c) {
  return __builtin_amdgcn_mfma_f32_32x32x16_bf16(a, b, c, 0, 0, 0);
}
__device__ __forceinline__ f32x4 mfma16(s16x8 a, s16x8 b, f32x4 c) {
  return __builtin_amdgcn_mfma_f32_16x16x32_bf16(a, b, c, 0, 0, 0);
}

// ---------------- kernel 1: weights f32 -> bf16 (+ Q scale fold, knmax init) ----------------
__global__ void prep_w(const float* __restrict__ Wq, const float* __restrict__ Wk,
                       const float* __restrict__ Wv, u16* __restrict__ dst,
                       u32* __restrict__ knmax_u) {
  int idx = blockIdx.x * 256 + threadIdx.x;   // 0 .. 98303
  if (blockIdx.x == 0 && threadIdx.x < 8) knmax_u[threadIdx.x] = 0u;
  float v;
  if (idx < 16384)        v = Wq[idx] * QSCL;
  else if (idx < 32768)   v = Wk[idx - 16384];
  else                    v = Wv[idx - 32768];
  dst[idx] = f2bf(v);
}

// ---------------- kernel 2: fused Q / KV projections (one launch, 1024 blocks) ----------------
__global__ __launch_bounds__(256) void proj_all(
    const float* __restrict__ sem, const float* __restrict__ foren,
    const u16* __restrict__ Wqb, const u16* __restrict__ Wkb, const u16* __restrict__ Wvb,
    const float* __restrict__ bq, const float* __restrict__ bk, const float* __restrict__ bv,
    u16* __restrict__ Qo, u16* __restrict__ Ko, u16* __restrict__ Vo,
    float* __restrict__ qnsq, u32* __restrict__ knmax_u) {
  __shared__ u16 lds[16384];  // X^T [64 px][256 c], swizzled
  const bool qpath = blockIdx.x < 512;
  const int bid = qpath ? blockIdx.x : blockIdx.x - 512;
  const int t = threadIdx.x, b = bid & 7, n0 = (bid >> 3) * 64;
  const float* X = qpath ? sem : foren;
  {
    const int px = t & 63, cb = (t >> 6) * 8, swz = (px & 31) * 8;
    for (int i = 0; i < 8; ++i) {
      int c0 = i * 32 + cb;
      size_t gb = ((size_t)b * DIM + c0) * HW + n0 + px;
      s16x8 us;
#pragma unroll
      for (int j = 0; j < 8; ++j) us[j] = (short)f2bf(X[gb + (size_t)j * HW]);
      *(s16x8*)(lds + px * 256 + (c0 ^ swz)) = us;
    }
  }
  __syncthreads();
  const int w = t >> 6, lane = t & 63, l15 = lane & 15, g = lane >> 4;

  if (qpath) {
    const int px = w * 16 + l15;
    s16x8 bx[8];
#pragma unroll
    for (int kc = 0; kc < 8; ++kc)
      bx[kc] = *(const s16x8*)(lds + px * 256 + (((kc * 4 + g) ^ (px & 31)) * 8));
    float nrm = 0.f;
#pragma unroll
    for (int ct = 0; ct < 4; ++ct) {
      f32x4 bb = *(const f32x4*)(bq + ct * 16 + 4 * g);
      f32x4 acc;
#pragma unroll
      for (int j = 0; j < 4; ++j) acc[j] = bb[j] * QSCL;
#pragma unroll
      for (int kc = 0; kc < 8; ++kc) {
        s16x8 aw = *(const s16x8*)(Wqb + (ct * 16 + l15) * 256 + kc * 32 + g * 8);
        acc = mfma16(aw, bx[kc], acc);
      }
      u32 lo = (u32)f2bf(acc[0]) | ((u32)f2bf(acc[1]) << 16);
      u32 hi = (u32)f2bf(acc[2]) | ((u32)f2bf(acc[3]) << 16);
      u32x2 pk; pk[0] = lo; pk[1] = hi;
      *(u32x2*)(Qo + ((size_t)b * HW + n0 + px) * 64 + ct * 16 + 4 * g) = pk;
#pragma unroll
      for (int j = 0; j < 4; ++j) nrm += acc[j] * acc[j];
    }
    nrm += __shfl_xor(nrm, 16);
    nrm += __shfl_xor(nrm, 32);
    if (g == 0) qnsq[(size_t)b * HW + n0 + px] = nrm;
    return;
  }
  // ---- K ----
  {
    const int px = w * 16 + l15;
    s16x8 bx[8];
#pragma unroll
    for (int kc = 0; kc < 8; ++kc)
      bx[kc] = *(const s16x8*)(lds + px * 256 + (((kc * 4 + g) ^ (px & 31)) * 8));
    float nrm = 0.f;
#pragma unroll
    for (int ct = 0; ct < 4; ++ct) {
      f32x4 acc = *(const f32x4*)(bk + ct * 16 + 4 * g);
#pragma unroll
      for (int kc = 0; kc < 8; ++kc) {
        s16x8 aw = *(const s16x8*)(Wkb + (ct * 16 + l15) * 256 + kc * 32 + g * 8);
        acc = mfma16(aw, bx[kc], acc);
      }
      u32 lo = (u32)f2bf(acc[0]) | ((u32)f2bf(acc[1]) << 16);
      u32 hi = (u32)f2bf(acc[2]) | ((u32)f2bf(acc[3]) << 16);
      u32x2 pk; pk[0] = lo; pk[1] = hi;
      *(u32x2*)(Ko + ((size_t)b * HW + n0 + px) * 64 + ct * 16 + 4 * g) = pk;
#pragma unroll
      for (int j = 0; j < 4; ++j) nrm += acc[j] * acc[j];
    }
    nrm += __shfl_xor(nrm, 16);
    nrm += __shfl_xor(nrm, 32);
    nrm = fmaxf(nrm, __shfl_xor(nrm, 1));
    nrm = fmaxf(nrm, __shfl_xor(nrm, 2));
    nrm = fmaxf(nrm, __shfl_xor(nrm, 4));
    nrm = fmaxf(nrm, __shfl_xor(nrm, 8));
    if (lane == 0) atomicMax(knmax_u + b, __float_as_uint(nrm));
  }
  // ---- V ----
#pragma unroll
  for (int ct2 = 0; ct2 < 4; ++ct2) {
    const int c0 = w * 64 + ct2 * 16;
    s16x8 aw[8];
#pragma unroll
    for (int kc = 0; kc < 8; ++kc)
      aw[kc] = *(const s16x8*)(Wvb + (c0 + l15) * 256 + kc * 32 + g * 8);
#pragma unroll
    for (int pxt = 0; pxt < 4; ++pxt) {
      const int px = pxt * 16 + l15;
      f32x4 acc = *(const f32x4*)(bv + c0 + 4 * g);
#pragma unroll
      for (int kc = 0; kc < 8; ++kc) {
        s16x8 bxp = *(const s16x8*)(lds + px * 256 + (((kc * 4 + g) ^ (px & 31)) * 8));
        acc = mfma16(aw[kc], bxp, acc);
      }
#pragma unroll
      for (int j = 0; j < 4; ++j)
        Vo[((size_t)b * DIM + c0 + 4 * g + j) * HW + n0 + pxt * 16 + l15] = f2bf(acc[j]);
    }
  }
}

// ---------------- kernel 3: fused attention, P-in-register (permlane), 1 barrier/tile ----------------
// 512 threads = 8 waves; wave w: qg=w>>2 (64 qrows), hh=(w>>1)&1 (32 keys), cg=w&1 (128 ch).
// QK: S^T = mfma32(K, Q) for keys[32hh,+32) x qrows[64qg,+64)  (dup x2 across cg)
// softmax: in-register (C-init = -m^, exp2, cvt_pk + permlane32_swap -> PV B-frags)
// PV: O[128ch x 64q] += mfma32(V_frag, P_frag) over the wave's 32 keys
// merge: hh-pairs summed via LDS in 2 rounds at the end.
// LDS bytes: K0@0 K1@8192 | V0@16384 V1@49152 (end 81920) | merge reuses 0..65536, l@65536
__global__ __launch_bounds__(512, 2) void attn5(
    const u16* __restrict__ Qg, const u16* __restrict__ Kg, const u16* __restrict__ Vg,
    const float* __restrict__ qnsq, const u32* __restrict__ knmax_u,
    const float* __restrict__ sem, const float* __restrict__ gamma_p,
    float* __restrict__ out) {
  __shared__ u16 lds[40960];
  char* ldsb = (char*)lds;
  const int t = threadIdx.x;
  const int b = blockIdx.x & 7;            // batch -> XCD (Q/K/V ~3MB L2-pinned)
  const int n0 = (blockIdx.x >> 3) << 7;   // *128
  const int w = t >> 6, lane = t & 63;
  const int l31 = lane & 31, g5 = lane >> 5;
  const int qg = w >> 2, hh = (w >> 1) & 1, cg = w & 1;

  const u16* Qb = Qg + (size_t)b * HW * 64;
  const u16* Kb = Kg + (size_t)b * HW * 64;
  const u16* Vb = Vg + (size_t)b * DIM * HW;

  // ---- QK state ----
  const int key = hh * 32 + l31;
  int ka[4];
#pragma unroll
  for (int ks = 0; ks < 4; ++ks)
    ka[ks] = key * 128 + (((ks * 2 + g5) ^ (key & 7)) * 16);
  s16x8 qb0[4], qb1[4];
#pragma unroll
  for (int ks = 0; ks < 4; ++ks) {
    qb0[ks] = *(const s16x8*)(Qb + (size_t)(n0 + qg * 64 + l31) * 64 + ks * 16 + g5 * 8);
    qb1[ks] = *(const s16x8*)(Qb + (size_t)(n0 + qg * 64 + 32 + l31) * 64 + ks * 16 + g5 * 8);
  }
  const float knsq = __uint_as_float(knmax_u[b]);
  const float mneg0 = -(sqrtf(qnsq[(size_t)b * HW + n0 + qg * 64 + l31] * knsq) * 1.02f);
  const float mneg1 = -(sqrtf(qnsq[(size_t)b * HW + n0 + qg * 64 + 32 + l31] * knsq) * 1.02f);

  // ---- PV state ----
  int va[4][2];
#pragma unroll
  for (int cb = 0; cb < 4; ++cb) {
    int c = cg * 128 + cb * 32 + l31;
#pragma unroll
    for (int s = 0; s < 2; ++s)
      va[cb][s] = c * 128 + (((hh * 4 + s * 2 + g5) ^ (c & 7)) * 16);
  }
  f32x16 O[4][2] = {};
  float lr0 = 0.f, lr1 = 0.f;

  // ---- staging (incremented pointers; linear LDS dest, inverse-swizzled source) ----
  const int srow = lane >> 3;
  const int sx = ((lane & 7) ^ srow) * 8;
  const u16* kp  = Kb + (size_t)(w * 8 + srow) * 64 + sx;
  const u16* vp0 = Vb + (size_t)((0 * 8 + w) * 8 + srow) * HW + sx;
  const u16* vp1 = Vb + (size_t)((1 * 8 + w) * 8 + srow) * HW + sx;
  const u16* vp2 = Vb + (size_t)((2 * 8 + w) * 8 + srow) * HW + sx;
  const u16* vp3 = Vb + (size_t)((3 * 8 + w) * 8 + srow) * HW + sx;

  auto STAGE = [&](int kdst, int vdst) {
    gload_lds16(kp,  (void*)(lds + kdst + w * 512));            kp  += 4096;
    gload_lds16(vp0, (void*)(lds + vdst + (0 * 8 + w) * 512));  vp0 += 64;
    gload_lds16(vp1, (void*)(lds + vdst + (1 * 8 + w) * 512));  vp1 += 64;
    gload_lds16(vp2, (void*)(lds + vdst + (2 * 8 + w) * 512));  vp2 += 64;
    gload_lds16(vp3, (void*)(lds + vdst + (3 * 8 + w) * 512));  vp3 += 64;
  };

  s16x8 pb0[2], pb1[2];

  auto tile = [&](auto BUFC, bool dostage) {
    constexpr int BUF = decltype(BUFC)::value;
    if (dostage) STAGE((BUF ^ 1) * 4096, 8192 + (BUF ^ 1) * 16384);
    // ---- K fragments (shared across both q-halves) ----
    s16x8 kf[4];
#pragma unroll
    for (int ks = 0; ks < 4; ++ks)
      kf[ks] = *(const s16x8*)(ldsb + BUF * 8192 + ka[ks]);
    // ---- S^T + in-register softmax, per q-half ----
#pragma unroll
    for (int qh = 0; qh < 2; ++qh) {
      const float mneg = qh == 0 ? mneg0 : mneg1;
      f32x16 sc;
#pragma unroll
      for (int r = 0; r < 16; ++r) sc[r] = mneg;   // C-init = -m^ (fold the shift)
#pragma unroll
      for (int ks = 0; ks < 4; ++ks)
        sc = mfma32(kf[ks], qh == 0 ? qb0[ks] : qb1[ks], sc);
      float p[16];
#pragma unroll
      for (int r = 0; r < 16; ++r) p[r] = fexp2(sc[r]);
      float rs = ((p[0] + p[1]) + (p[2] + p[3])) + ((p[4] + p[5]) + (p[6] + p[7])) +
                 ((p[8] + p[9]) + (p[10] + p[11])) + ((p[12] + p[13]) + (p[14] + p[15]));
      if (qh == 0) lr0 += rs; else lr1 += rs;
#pragma unroll
      for (int s = 0; s < 2; ++s) {
        u32 x1 = cvtpk(p[s * 8 + 0], p[s * 8 + 1]);
        u32 x2 = cvtpk(p[s * 8 + 2], p[s * 8 + 3]);
        u32 y1 = cvtpk(p[s * 8 + 4], p[s * 8 + 5]);
        u32 y2 = cvtpk(p[s * 8 + 6], p[s * 8 + 7]);
        u32x2 r1 = __builtin_amdgcn_permlane32_swap(x1, y1, false, false);
        u32x2 r2 = __builtin_amdgcn_permlane32_swap(x2, y2, false, false);
        union { u32 wv[4]; s16x8 v; } u;
        u.wv[0] = r1[0]; u.wv[1] = r2[0]; u.wv[2] = r1[1]; u.wv[3] = r2[1];
        if (qh == 0) pb0[s] = u.v; else pb1[s] = u.v;
      }
    }
    // ---- O += V^T-frag x P-frag (all from this wave's registers + V LDS) ----
#pragma unroll
    for (int cb = 0; cb < 4; ++cb) {
      s16x8 v0 = *(const s16x8*)(ldsb + 16384 + BUF * 32768 + va[cb][0]);
      s16x8 v1 = *(const s16x8*)(ldsb + 16384 + BUF * 32768 + va[cb][1]);
      O[cb][0] = mfma32(v0, pb0[0], O[cb][0]);
      O[cb][0] = mfma32(v1, pb0[1], O[cb][0]);
      O[cb][1] = mfma32(v0, pb1[0], O[cb][1]);
      O[cb][1] = mfma32(v1, pb1[1], O[cb][1]);
    }
    __syncthreads();   // single barrier: staging landed (vmcnt) + buffers consumed
  };

  STAGE(0, 8192);
  __syncthreads();
  for (int kt = 0; kt < 64; kt += 2) {
    tile(ic<0>{}, true);
    tile(ic<1>{}, kt + 2 < 64);
  }

  // ---- merge hh-pairs + epilogue (2 rounds; I/O split across waves) ----
  float ls0 = lr0 + __shfl_xor(lr0, 32);
  float ls1 = lr1 + __shfl_xor(lr1, 32);
  float* lfp = (float*)(ldsb + 65536);
  if (cg == 0 && lane < 32) {
    lfp[hh * 128 + qg * 64 + l31] = ls0;
    lfp[hh * 128 + qg * 64 + 32 + l31] = ls1;
  }
  const int mb = (qg * 2 + cg) * 16384;
  const float gm = gamma_p[0];
#pragma unroll
  for (int r = 0; r < 2; ++r) {
    __syncthreads();
    if (hh != r) {   // writer half
#pragma unroll
      for (int cb = 0; cb < 4; ++cb) {
#pragma unroll
        for (int qd = 0; qd < 4; ++qd) {
          f32x4 tq;
          tq[0] = O[cb][r][qd * 4 + 0]; tq[1] = O[cb][r][qd * 4 + 1];
          tq[2] = O[cb][r][qd * 4 + 2]; tq[3] = O[cb][r][qd * 4 + 3];
          *(f32x4*)(ldsb + mb + cb * 4096 + l31 * 128 + ((((qd << 1) | g5) ^ (l31 & 7)) * 16)) = tq;
        }
      }
    }
    __syncthreads();
    if (hh == r) {   // merger + epilogue half
      float ltot = (r == 0 ? ls0 : ls1) + lfp[(1 - r) * 128 + qg * 64 + r * 32 + l31];
      float gi = gm * __builtin_amdgcn_rcpf(ltot);
      const int n = n0 + qg * 64 + r * 32 + l31;
#pragma unroll
      for (int cb = 0; cb < 4; ++cb) {
        f32x16 o = O[cb][r];
#pragma unroll
        for (int qd = 0; qd < 4; ++qd) {
          f32x4 part = *(const f32x4*)(ldsb + mb + cb * 4096 + l31 * 128 + ((((qd << 1) | g5) ^ (l31 & 7)) * 16));
          o[qd * 4 + 0] += part[0]; o[qd * 4 + 1] += part[1];
          o[qd * 4 + 2] += part[2]; o[qd * 4 + 3] += part[3];
        }
#pragma unroll
        for (int rg = 0; rg < 16; ++rg) {
          int c = cg * 128 + cb * 32 + (rg & 3) + 8 * (rg >> 2) + 4 * g5;
          size_t idx = ((size_t)b * DIM + c) * HW + n;
          out[idx] = sem[idx] + gi * o[rg];
        }
      }
    }
  }
}

extern "C" void kernel_launch(void* const* d_in, const int* in_sizes, int n_in,
                              void* d_out, int out_size, void* d_ws, size_t ws_size,
                              hipStream_t stream) {
  const float* sem   = (const float*)d_in[0];
  const float* foren = (const float*)d_in[1];
  const float* Wq    = (const float*)d_in[2];
  const float* bq    = (const float*)d_in[3];
  const float* Wk    = (const float*)d_in[4];
  const float* bk    = (const float*)d_in[5];
  const float* Wv    = (const float*)d_in[6];
  const float* bv    = (const float*)d_in[7];
  const float* gamma = (const float*)d_in[8];
  float* out = (float*)d_out;

  // ws (u16 units): Wq 16K | Wk 16K | Wv 64K | Q 2M | K 2M | V 8M | qnsq f32 32K | knmax u32 8
  u16* Wqb = (u16*)d_ws;
  u16* Wkb = Wqb + 16384;
  u16* Wvb = Wkb + 16384;
  u16* Q   = Wvb + 65536;
  u16* K   = Q + (size_t)NB * HW * 64;
  u16* V   = K + (size_t)NB * HW * 64;
  float* qnsq = (float*)(V + (size_t)NB * DIM * HW);
  u32* knmax_u = (u32*)(qnsq + (size_t)NB * HW);

  prep_w  <<<384, 256, 0, stream>>>(Wq, Wk, Wv, Wqb, knmax_u);
  proj_all<<<1024, 256, 0, stream>>>(sem, foren, Wqb, Wkb, Wvb, bq, bk, bv, Q, K, V, qnsq, knmax_u);
  attn5   <<<256, 512, 0, stream>>>(Q, K, V, qnsq, knmax_u, sem, gamma, out);
}

// Round 10
// 155.875 us; speedup vs baseline: 2.0057x; 2.0057x over previous
//
#include <hip/hip_runtime.h>
#include <stdint.h>

typedef unsigned short u16;
typedef unsigned int u32;
typedef short s16x8 __attribute__((ext_vector_type(8)));
typedef float f32x4 __attribute__((ext_vector_type(4)));
typedef float f32x16 __attribute__((ext_vector_type(16)));
typedef u32 u32x2 __attribute__((ext_vector_type(2)));

#define DIM 256
#define HW  4096
#define NB  8
#define QSCL 0.18033688011112042f   // 0.125 * log2(e): softmax scale + log2-domain folded into Q

template <int N> struct ic { static constexpr int value = N; };

__device__ __forceinline__ u16 f2bf(float f) {
  union { float f; unsigned u; } v; v.f = f;
  unsigned r = v.u + 0x7FFFu + ((v.u >> 16) & 1u);
  return (u16)(r >> 16);
}
__device__ __forceinline__ float fexp2(float x) { return __builtin_amdgcn_exp2f(x); }
__device__ __forceinline__ u32 cvtpk(float a, float b) {
  u32 r; asm("v_cvt_pk_bf16_f32 %0, %1, %2" : "=v"(r) : "v"(a), "v"(b)); return r;
}

typedef __attribute__((address_space(1))) const void gvoid_c;
typedef __attribute__((address_space(3))) void lvoid;
__device__ __forceinline__ void gload_lds16(const void* g, void* l) {
  __builtin_amdgcn_global_load_lds((gvoid_c*)g, (lvoid*)l, 16, 0, 0);
}
__device__ __forceinline__ f32x16 mfma32(s16x8 a, s16x8 b, f32x16 c) {
  return __builtin_amdgcn_mfma_f32_32x32x16_bf16(a, b, c, 0, 0, 0);
}
__device__ __forceinline__ f32x4 mfma16(s16x8 a, s16x8 b, f32x4 c) {
  return __builtin_amdgcn_mfma_f32_16x16x32_bf16(a, b, c, 0, 0, 0);
}

// ---------------- kernel 1: weights f32 -> bf16 (+ Q scale fold, knmax init) ----------------
__global__ void prep_w(const float* __restrict__ Wq, const float* __restrict__ Wk,
                       const float* __restrict__ Wv, u16* __restrict__ dst,
                       u32* __restrict__ knmax_u) {
  int idx = blockIdx.x * 256 + threadIdx.x;   // 0 .. 98303
  if (blockIdx.x == 0 && threadIdx.x < 8) knmax_u[threadIdx.x] = 0u;
  float v;
  if (idx < 16384)        v = Wq[idx] * QSCL;
  else if (idx < 32768)   v = Wk[idx - 16384];
  else                    v = Wv[idx - 32768];
  dst[idx] = f2bf(v);
}

// ---------------- kernel 2: fused Q / KV projections (one launch, 1024 blocks) ----------------
__global__ __launch_bounds__(256) void proj_all(
    const float* __restrict__ sem, const float* __restrict__ foren,
    const u16* __restrict__ Wqb, const u16* __restrict__ Wkb, const u16* __restrict__ Wvb,
    const float* __restrict__ bq, const float* __restrict__ bk, const float* __restrict__ bv,
    u16* __restrict__ Qo, u16* __restrict__ Ko, u16* __restrict__ Vo,
    float* __restrict__ qnsq, u32* __restrict__ knmax_u) {
  __shared__ u16 lds[16384];  // X^T [64 px][256 c], swizzled
  const bool qpath = blockIdx.x < 512;
  const int bid = qpath ? blockIdx.x : blockIdx.x - 512;
  const int t = threadIdx.x, b = bid & 7, n0 = (bid >> 3) * 64;
  const float* X = qpath ? sem : foren;
  {
    const int px = t & 63, cb = (t >> 6) * 8, swz = (px & 31) * 8;
    for (int i = 0; i < 8; ++i) {
      int c0 = i * 32 + cb;
      size_t gb = ((size_t)b * DIM + c0) * HW + n0 + px;
      s16x8 us;
#pragma unroll
      for (int j = 0; j < 8; ++j) us[j] = (short)f2bf(X[gb + (size_t)j * HW]);
      *(s16x8*)(lds + px * 256 + (c0 ^ swz)) = us;
    }
  }
  __syncthreads();
  const int w = t >> 6, lane = t & 63, l15 = lane & 15, g = lane >> 4;

  if (qpath) {
    const int px = w * 16 + l15;
    s16x8 bx[8];
#pragma unroll
    for (int kc = 0; kc < 8; ++kc)
      bx[kc] = *(const s16x8*)(lds + px * 256 + (((kc * 4 + g) ^ (px & 31)) * 8));
    float nrm = 0.f;
#pragma unroll
    for (int ct = 0; ct < 4; ++ct) {
      f32x4 bb = *(const f32x4*)(bq + ct * 16 + 4 * g);
      f32x4 acc;
#pragma unroll
      for (int j = 0; j < 4; ++j) acc[j] = bb[j] * QSCL;
#pragma unroll
      for (int kc = 0; kc < 8; ++kc) {
        s16x8 aw = *(const s16x8*)(Wqb + (ct * 16 + l15) * 256 + kc * 32 + g * 8);
        acc = mfma16(aw, bx[kc], acc);
      }
      u32 lo = (u32)f2bf(acc[0]) | ((u32)f2bf(acc[1]) << 16);
      u32 hi = (u32)f2bf(acc[2]) | ((u32)f2bf(acc[3]) << 16);
      u32x2 pk; pk[0] = lo; pk[1] = hi;
      *(u32x2*)(Qo + ((size_t)b * HW + n0 + px) * 64 + ct * 16 + 4 * g) = pk;
#pragma unroll
      for (int j = 0; j < 4; ++j) nrm += acc[j] * acc[j];
    }
    nrm += __shfl_xor(nrm, 16);
    nrm += __shfl_xor(nrm, 32);
    if (g == 0) qnsq[(size_t)b * HW + n0 + px] = nrm;
    return;
  }
  // ---- K ----
  {
    const int px = w * 16 + l15;
    s16x8 bx[8];
#pragma unroll
    for (int kc = 0; kc < 8; ++kc)
      bx[kc] = *(const s16x8*)(lds + px * 256 + (((kc * 4 + g) ^ (px & 31)) * 8));
    float nrm = 0.f;
#pragma unroll
    for (int ct = 0; ct < 4; ++ct) {
      f32x4 acc = *(const f32x4*)(bk + ct * 16 + 4 * g);
#pragma unroll
      for (int kc = 0; kc < 8; ++kc) {
        s16x8 aw = *(const s16x8*)(Wkb + (ct * 16 + l15) * 256 + kc * 32 + g * 8);
        acc = mfma16(aw, bx[kc], acc);
      }
      u32 lo = (u32)f2bf(acc[0]) | ((u32)f2bf(acc[1]) << 16);
      u32 hi = (u32)f2bf(acc[2]) | ((u32)f2bf(acc[3]) << 16);
      u32x2 pk; pk[0] = lo; pk[1] = hi;
      *(u32x2*)(Ko + ((size_t)b * HW + n0 + px) * 64 + ct * 16 + 4 * g) = pk;
#pragma unroll
      for (int j = 0; j < 4; ++j) nrm += acc[j] * acc[j];
    }
    nrm += __shfl_xor(nrm, 16);
    nrm += __shfl_xor(nrm, 32);
    nrm = fmaxf(nrm, __shfl_xor(nrm, 1));
    nrm = fmaxf(nrm, __shfl_xor(nrm, 2));
    nrm = fmaxf(nrm, __shfl_xor(nrm, 4));
    nrm = fmaxf(nrm, __shfl_xor(nrm, 8));
    if (lane == 0) atomicMax(knmax_u + b, __float_as_uint(nrm));
  }
  // ---- V ----
#pragma unroll
  for (int ct2 = 0; ct2 < 4; ++ct2) {
    const int c0 = w * 64 + ct2 * 16;
    s16x8 aw[8];
#pragma unroll
    for (int kc = 0; kc < 8; ++kc)
      aw[kc] = *(const s16x8*)(Wvb + (c0 + l15) * 256 + kc * 32 + g * 8);
#pragma unroll
    for (int pxt = 0; pxt < 4; ++pxt) {
      const int px = pxt * 16 + l15;
      f32x4 acc = *(const f32x4*)(bv + c0 + 4 * g);
#pragma unroll
      for (int kc = 0; kc < 8; ++kc) {
        s16x8 bxp = *(const s16x8*)(lds + px * 256 + (((kc * 4 + g) ^ (px & 31)) * 8));
        acc = mfma16(aw[kc], bxp, acc);
      }
#pragma unroll
      for (int j = 0; j < 4; ++j)
        Vo[((size_t)b * DIM + c0 + 4 * g + j) * HW + n0 + pxt * 16 + l15] = f2bf(acc[j]);
    }
  }
}

// ---------------- kernel 3: fused attention — 1 barrier/tile, counted vmcnt ----------------
// 512 threads = 8 waves, Q-tile 128, KV-tile 64 (attn3's verified tile math).
// Region r: barrier; stage K(r+2)->KB[r&1], V(r+2)->VB[(r+2)%3]; QK(r+1) rd KB[(r+1)&1]
//   wr PB[(r+1)&1]; PV(r) rd PB[r&1], VB[r%3]; vmcnt(4) lgkmcnt(0).
// vmcnt(4) leaves only this region's 4 V loads (FIFO retire) -> K lands in issue region,
// V by end of next. K dbuf / V 3-buf / P dbuf (16KB slots) alias-free.
// r9 BUGFIX: STAGE destinations are BYTE offsets -> must index ldsb (char*), not lds (u16*).
//   attn8/9/10 staged K into PB0 and V ~50KB off-target (u16-indexed byte offsets) -> NaN.
// LDS bytes: KB 0/8192 | PB 16384/32768 | lsum 49152 | VB 50176/82944/115712 | end 148480
__global__ __launch_bounds__(512, 1) void attn11(
    const u16* __restrict__ Qg, const u16* __restrict__ Kg, const u16* __restrict__ Vg,
    const float* __restrict__ qnsq, const u32* __restrict__ knmax_u,
    const float* __restrict__ sem, const float* __restrict__ gamma_p,
    float* __restrict__ out) {
  __shared__ u16 lds[74240];   // 148480 B
  char* ldsb = (char*)lds;
  const int t = threadIdx.x;
  const int b = blockIdx.x & 7;            // batch -> XCD (Q/K/V ~3MB L2-pinned)
  const int n0 = (blockIdx.x >> 3) << 7;   // *128
  const int w = t >> 6, lane = t & 63;
  const int l31 = lane & 31, g5 = lane >> 5;

  const u16* Qb = Qg + (size_t)b * HW * 64;
  const u16* Kb = Kg + (size_t)b * HW * 64;
  const u16* Vb = Vg + (size_t)b * DIM * HW;

  // ---- QK roles: wave (hh=w>>2, rr=w&3): keys hh*32, qrows rr*32 ----
  const int hh = w >> 2, rr = w & 3;
  const int key0 = hh * 32 + l31;
  const int qrow = rr * 32 + l31;
  int ka[4];
#pragma unroll
  for (int ks = 0; ks < 4; ++ks)
    ka[ks] = key0 * 128 + (((ks * 2 + g5) ^ (key0 & 7)) * 16);
  s16x8 qb[4];
#pragma unroll
  for (int ks = 0; ks < 4; ++ks)
    qb[ks] = *(const s16x8*)(Qb + (size_t)(n0 + qrow) * 64 + ks * 16 + g5 * 8);
  int pw_[4];
#pragma unroll
  for (int jg = 0; jg < 4; ++jg)
    pw_[jg] = qrow * 128 + (((hh * 4 + jg) ^ (qrow & 7)) * 16) + g5 * 8;
  const float mneg = -(sqrtf(qnsq[(size_t)b * HW + n0 + qrow] * __uint_as_float(knmax_u[b])) * 1.02f);

  // ---- PV roles: wave (rw=w>>2, cw=w&3): rows rw*64, channels cw*64 ----
  const int rw = w >> 2, cw = w & 3;
  int pa[2][4], va[2][4];
#pragma unroll
  for (int rt = 0; rt < 2; ++rt)
#pragma unroll
    for (int ks = 0; ks < 4; ++ks) {
      int r = rw * 64 + rt * 32 + l31;
      pa[rt][ks] = r * 128 + (((ks * 2 + g5) ^ (r & 7)) * 16);
    }
#pragma unroll
  for (int ct = 0; ct < 2; ++ct)
#pragma unroll
    for (int ks = 0; ks < 4; ++ks) {
      int c = cw * 64 + ct * 32 + l31;
      va[ct][ks] = 50176 + c * 128 + (((ks * 2 + g5) ^ (c & 7)) * 16);  // absolute bytes, VB0
    }

  f32x16 O[4] = {};
  float lreg = 0.f;

  // ---- staging: incremented pointers; linear LDS dest, inverse-swizzled global source ----
  const int srow = lane >> 3;
  const int sx = ((lane & 7) ^ srow) * 8;
  const u16* kp  = Kb + (size_t)(w * 8 + srow) * 64 + sx;
  const u16* vp0 = Vb + (size_t)((0 * 8 + w) * 8 + srow) * HW + sx;
  const u16* vp1 = Vb + (size_t)((1 * 8 + w) * 8 + srow) * HW + sx;
  const u16* vp2 = Vb + (size_t)((2 * 8 + w) * 8 + srow) * HW + sx;
  const u16* vp3 = Vb + (size_t)((3 * 8 + w) * 8 + srow) * HW + sx;

  auto STAGE_K = [&](int dstB) {   // dstB: BYTE offset; wave chunk = 1024 B
    gload_lds16(kp, (void*)(ldsb + dstB + w * 1024)); kp += 4096;
  };
  auto STAGE_V = [&](int dstB) {   // 4 chunks/wave, 1024 B each
    gload_lds16(vp0, (void*)(ldsb + dstB + (0 * 8 + w) * 1024)); vp0 += 64;
    gload_lds16(vp1, (void*)(ldsb + dstB + (1 * 8 + w) * 1024)); vp1 += 64;
    gload_lds16(vp2, (void*)(ldsb + dstB + (2 * 8 + w) * 1024)); vp2 += 64;
    gload_lds16(vp3, (void*)(ldsb + dstB + (3 * 8 + w) * 1024)); vp3 += 64;
  };

  auto do_qk = [&](auto KRC, auto PWC) {
    constexpr int KR = decltype(KRC)::value;
    constexpr int PW = decltype(PWC)::value;
    f32x16 sc;
#pragma unroll
    for (int r = 0; r < 16; ++r) sc[r] = mneg;   // fold -m^ into C-init
#pragma unroll
    for (int ks = 0; ks < 4; ++ks) {
      s16x8 kf = *(const s16x8*)(ldsb + KR + ka[ks]);
      sc = mfma32(kf, qb[ks], sc);
    }
#pragma unroll
    for (int jg = 0; jg < 4; ++jg) {
      float p0 = fexp2(sc[jg * 4 + 0]);
      float p1 = fexp2(sc[jg * 4 + 1]);
      float p2 = fexp2(sc[jg * 4 + 2]);
      float p3 = fexp2(sc[jg * 4 + 3]);
      lreg += (p0 + p1) + (p2 + p3);
      u32 w0 = cvtpk(p0, p1), w1 = cvtpk(p2, p3);
      u32x2 pk; pk[0] = w0; pk[1] = w1;
      *(u32x2*)(ldsb + PW + pw_[jg]) = pk;
    }
  };

  auto do_pv = [&](auto PRC) {
    constexpr int PR = decltype(PRC)::value;
    __builtin_amdgcn_s_setprio(1);
#pragma unroll
    for (int ks = 0; ks < 4; ++ks) {
      s16x8 ap0 = *(const s16x8*)(ldsb + PR + pa[0][ks]);
      s16x8 ap1 = *(const s16x8*)(ldsb + PR + pa[1][ks]);
      s16x8 vb0 = *(const s16x8*)(ldsb + va[0][ks]);
      s16x8 vb1 = *(const s16x8*)(ldsb + va[1][ks]);
      O[0] = mfma32(ap0, vb0, O[0]);
      O[1] = mfma32(ap0, vb1, O[1]);
      O[2] = mfma32(ap1, vb0, O[2]);
      O[3] = mfma32(ap1, vb1, O[3]);
    }
    __builtin_amdgcn_s_setprio(0);
  };

  // region r: barrier; stage K(r+2),V(r+2); QK(r+1); PV(r); vmcnt(4)+lgkmcnt(0)
  auto iter = [&](auto PARC, auto VBC, bool qk_next) {
    constexpr int PAR = decltype(PARC)::value;   // r & 1
    constexpr int VB  = decltype(VBC)::value;    // r % 3
    __builtin_amdgcn_s_barrier();
    __builtin_amdgcn_sched_barrier(0);
    STAGE_K(PAR * 8192);                               // K(r+2) -> KB[r&1]
    STAGE_V(50176 + ((VB + 2) % 3) * 32768);           // V(r+2) -> VB[(r+2)%3]
    if (qk_next)
      do_qk(ic<(PAR ^ 1) * 8192>{}, ic<16384 + (PAR ^ 1) * 16384>{});   // QK(r+1)
    do_pv(ic<16384 + PAR * 16384>{});                  // PV(r): PB[r&1], VB[r%3] via va
    // rotate V read addresses to next buffer
    constexpr int D = (VB == 2) ? -65536 : 32768;
#pragma unroll
    for (int ct = 0; ct < 2; ++ct)
#pragma unroll
      for (int ks = 0; ks < 4; ++ks) va[ct][ks] += D;
    asm volatile("s_waitcnt vmcnt(4) lgkmcnt(0)" ::: "memory");  // K(r+2), V(r+1) landed; P published
  };

  // ---- prologue: stage K(0),V(0),K(1),V(1); publish; QK(0) ----
  STAGE_K(0);
  STAGE_V(50176);
  STAGE_K(8192);
  STAGE_V(50176 + 32768);
  asm volatile("s_waitcnt vmcnt(4)" ::: "memory");   // K(0),V(0),K(1) landed; V(1) in flight
  __builtin_amdgcn_s_barrier();
  __builtin_amdgcn_sched_barrier(0);
  do_qk(ic<0>{}, ic<16384>{});                        // P(0) -> PB0
  asm volatile("s_waitcnt lgkmcnt(0)" ::: "memory");

  for (int kt = 0; kt < 60; kt += 6) {
    iter(ic<0>{}, ic<0>{}, true);
    iter(ic<1>{}, ic<1>{}, true);
    iter(ic<0>{}, ic<2>{}, true);
    iter(ic<1>{}, ic<0>{}, true);
    iter(ic<0>{}, ic<1>{}, true);
    iter(ic<1>{}, ic<2>{}, true);
  }
  iter(ic<0>{}, ic<0>{}, true);    // r=60
  iter(ic<1>{}, ic<1>{}, true);    // r=61
  iter(ic<0>{}, ic<2>{}, true);    // r=62 (stages tile 64: benign, lands unread in-ws)
  iter(ic<1>{}, ic<0>{}, false);   // r=63 (stages tile 65: benign)

  // ---- merge l across (g5, hh) then epilogue ----
  float* lfp = (float*)(ldsb + 49152);
  float ls = lreg + __shfl_xor(lreg, 32);
  if (lane < 32) lfp[hh * 128 + qrow] = ls;
  __syncthreads();
  const float gm = gamma_p[0];
#pragma unroll
  for (int rt = 0; rt < 2; ++rt) {
#pragma unroll
    for (int jg = 0; jg < 4; ++jg) {
      const int noff = rw * 64 + rt * 32 + jg * 8 + 4 * g5;
      f32x4 l0 = *(const f32x4*)(lfp + noff);
      f32x4 l1 = *(const f32x4*)(lfp + 128 + noff);
      f32x4 inv;
#pragma unroll
      for (int j = 0; j < 4; ++j) inv[j] = __builtin_amdgcn_rcpf(l0[j] + l1[j]);
#pragma unroll
      for (int ct = 0; ct < 2; ++ct) {
        const int c = cw * 64 + ct * 32 + l31;
        size_t base = ((size_t)b * DIM + c) * HW + n0 + noff;
        f32x4 sv = *(const f32x4*)(sem + base);
        f32x4 ov;
#pragma unroll
        for (int j = 0; j < 4; ++j)
          ov[j] = sv[j] + gm * (O[rt * 2 + ct][jg * 4 + j] * inv[j]);
        *(f32x4*)(out + base) = ov;
      }
    }
  }
}

extern "C" void kernel_launch(void* const* d_in, const int* in_sizes, int n_in,
                              void* d_out, int out_size, void* d_ws, size_t ws_size,
                              hipStream_t stream) {
  const float* sem   = (const float*)d_in[0];
  const float* foren = (const float*)d_in[1];
  const float* Wq    = (const float*)d_in[2];
  const float* bq    = (const float*)d_in[3];
  const float* Wk    = (const float*)d_in[4];
  const float* bk    = (const float*)d_in[5];
  const float* Wv    = (const float*)d_in[6];
  const float* bv    = (const float*)d_in[7];
  const float* gamma = (const float*)d_in[8];
  float* out = (float*)d_out;

  // ws (u16 units): Wq 16K | Wk 16K | Wv 64K | Q 2M | K 2M | V 8M | qnsq f32 32K | knmax u32 8
  u16* Wqb = (u16*)d_ws;
  u16* Wkb = Wqb + 16384;
  u16* Wvb = Wkb + 16384;
  u16* Q   = Wvb + 65536;
  u16* K   = Q + (size_t)NB * HW * 64;
  u16* V   = K + (size_t)NB * HW * 64;
  float* qnsq = (float*)(V + (size_t)NB * DIM * HW);
  u32* knmax_u = (u32*)(qnsq + (size_t)NB * HW);

  prep_w  <<<384, 256, 0, stream>>>(Wq, Wk, Wv, Wqb, knmax_u);
  proj_all<<<1024, 256, 0, stream>>>(sem, foren, Wqb, Wkb, Wvb, bq, bk, bv, Q, K, V, qnsq, knmax_u);
  attn11  <<<256, 512, 0, stream>>>(Q, K, V, qnsq, knmax_u, sem, gamma, out);
}

// Round 11
// 155.689 us; speedup vs baseline: 2.0081x; 1.0012x over previous
//
#include <hip/hip_runtime.h>
#include <stdint.h>

typedef unsigned short u16;
typedef unsigned int u32;
typedef short s16x8 __attribute__((ext_vector_type(8)));
typedef float f32x4 __attribute__((ext_vector_type(4)));
typedef float f32x16 __attribute__((ext_vector_type(16)));
typedef u32 u32x2 __attribute__((ext_vector_type(2)));

#define DIM 256
#define HW  4096
#define NB  8
#define QSCL 0.18033688011112042f   // 0.125 * log2(e): softmax scale + log2-domain folded into Q

template <int N> struct ic { static constexpr int value = N; };

__device__ __forceinline__ u16 f2bf(float f) {
  union { float f; unsigned u; } v; v.f = f;
  unsigned r = v.u + 0x7FFFu + ((v.u >> 16) & 1u);
  return (u16)(r >> 16);
}
__device__ __forceinline__ float fexp2(float x) { return __builtin_amdgcn_exp2f(x); }
__device__ __forceinline__ u32 cvtpk(float a, float b) {
  u32 r; asm("v_cvt_pk_bf16_f32 %0, %1, %2" : "=v"(r) : "v"(a), "v"(b)); return r;
}

typedef __attribute__((address_space(1))) const void gvoid_c;
typedef __attribute__((address_space(3))) void lvoid;
__device__ __forceinline__ void gload_lds16(const void* g, void* l) {
  __builtin_amdgcn_global_load_lds((gvoid_c*)g, (lvoid*)l, 16, 0, 0);
}
__device__ __forceinline__ f32x16 mfma32(s16x8 a, s16x8 b, f32x16 c) {
  return __builtin_amdgcn_mfma_f32_32x32x16_bf16(a, b, c, 0, 0, 0);
}
__device__ __forceinline__ f32x4 mfma16(s16x8 a, s16x8 b, f32x4 c) {
  return __builtin_amdgcn_mfma_f32_16x16x32_bf16(a, b, c, 0, 0, 0);
}

// ---------------- kernel 1: weights f32 -> bf16 (+ Q scale fold, knmax init) ----------------
__global__ void prep_w(const float* __restrict__ Wq, const float* __restrict__ Wk,
                       const float* __restrict__ Wv, u16* __restrict__ dst,
                       u32* __restrict__ knmax_u) {
  int idx = blockIdx.x * 256 + threadIdx.x;   // 0 .. 98303
  if (blockIdx.x == 0 && threadIdx.x < 8) knmax_u[threadIdx.x] = 0u;
  float v;
  if (idx < 16384)        v = Wq[idx] * QSCL;
  else if (idx < 32768)   v = Wk[idx - 16384];
  else                    v = Wv[idx - 32768];
  dst[idx] = f2bf(v);
}

// ---------------- kernel 2: fused Q / KV projections (one launch, 1024 blocks) ----------------
__global__ __launch_bounds__(256) void proj_all(
    const float* __restrict__ sem, const float* __restrict__ foren,
    const u16* __restrict__ Wqb, const u16* __restrict__ Wkb, const u16* __restrict__ Wvb,
    const float* __restrict__ bq, const float* __restrict__ bk, const float* __restrict__ bv,
    u16* __restrict__ Qo, u16* __restrict__ Ko, u16* __restrict__ Vo,
    float* __restrict__ qnsq, u32* __restrict__ knmax_u) {
  __shared__ u16 lds[16384];  // X^T [64 px][256 c], swizzled
  const bool qpath = blockIdx.x < 512;
  const int bid = qpath ? blockIdx.x : blockIdx.x - 512;
  const int t = threadIdx.x, b = bid & 7, n0 = (bid >> 3) * 64;
  const float* X = qpath ? sem : foren;
  {
    const int px = t & 63, cb = (t >> 6) * 8, swz = (px & 31) * 8;
    for (int i = 0; i < 8; ++i) {
      int c0 = i * 32 + cb;
      size_t gb = ((size_t)b * DIM + c0) * HW + n0 + px;
      s16x8 us;
#pragma unroll
      for (int j = 0; j < 8; ++j) us[j] = (short)f2bf(X[gb + (size_t)j * HW]);
      *(s16x8*)(lds + px * 256 + (c0 ^ swz)) = us;
    }
  }
  __syncthreads();
  const int w = t >> 6, lane = t & 63, l15 = lane & 15, g = lane >> 4;

  if (qpath) {
    const int px = w * 16 + l15;
    s16x8 bx[8];
#pragma unroll
    for (int kc = 0; kc < 8; ++kc)
      bx[kc] = *(const s16x8*)(lds + px * 256 + (((kc * 4 + g) ^ (px & 31)) * 8));
    float nrm = 0.f;
#pragma unroll
    for (int ct = 0; ct < 4; ++ct) {
      f32x4 bb = *(const f32x4*)(bq + ct * 16 + 4 * g);
      f32x4 acc;
#pragma unroll
      for (int j = 0; j < 4; ++j) acc[j] = bb[j] * QSCL;
#pragma unroll
      for (int kc = 0; kc < 8; ++kc) {
        s16x8 aw = *(const s16x8*)(Wqb + (ct * 16 + l15) * 256 + kc * 32 + g * 8);
        acc = mfma16(aw, bx[kc], acc);
      }
      u32 lo = (u32)f2bf(acc[0]) | ((u32)f2bf(acc[1]) << 16);
      u32 hi = (u32)f2bf(acc[2]) | ((u32)f2bf(acc[3]) << 16);
      u32x2 pk; pk[0] = lo; pk[1] = hi;
      *(u32x2*)(Qo + ((size_t)b * HW + n0 + px) * 64 + ct * 16 + 4 * g) = pk;
#pragma unroll
      for (int j = 0; j < 4; ++j) nrm += acc[j] * acc[j];
    }
    nrm += __shfl_xor(nrm, 16);
    nrm += __shfl_xor(nrm, 32);
    if (g == 0) qnsq[(size_t)b * HW + n0 + px] = nrm;
    return;
  }
  // ---- K ----
  {
    const int px = w * 16 + l15;
    s16x8 bx[8];
#pragma unroll
    for (int kc = 0; kc < 8; ++kc)
      bx[kc] = *(const s16x8*)(lds + px * 256 + (((kc * 4 + g) ^ (px & 31)) * 8));
    float nrm = 0.f;
#pragma unroll
    for (int ct = 0; ct < 4; ++ct) {
      f32x4 acc = *(const f32x4*)(bk + ct * 16 + 4 * g);
#pragma unroll
      for (int kc = 0; kc < 8; ++kc) {
        s16x8 aw = *(const s16x8*)(Wkb + (ct * 16 + l15) * 256 + kc * 32 + g * 8);
        acc = mfma16(aw, bx[kc], acc);
      }
      u32 lo = (u32)f2bf(acc[0]) | ((u32)f2bf(acc[1]) << 16);
      u32 hi = (u32)f2bf(acc[2]) | ((u32)f2bf(acc[3]) << 16);
      u32x2 pk; pk[0] = lo; pk[1] = hi;
      *(u32x2*)(Ko + ((size_t)b * HW + n0 + px) * 64 + ct * 16 + 4 * g) = pk;
#pragma unroll
      for (int j = 0; j < 4; ++j) nrm += acc[j] * acc[j];
    }
    nrm += __shfl_xor(nrm, 16);
    nrm += __shfl_xor(nrm, 32);
    nrm = fmaxf(nrm, __shfl_xor(nrm, 1));
    nrm = fmaxf(nrm, __shfl_xor(nrm, 2));
    nrm = fmaxf(nrm, __shfl_xor(nrm, 4));
    nrm = fmaxf(nrm, __shfl_xor(nrm, 8));
    if (lane == 0) atomicMax(knmax_u + b, __float_as_uint(nrm));
  }
  // ---- V ----
#pragma unroll
  for (int ct2 = 0; ct2 < 4; ++ct2) {
    const int c0 = w * 64 + ct2 * 16;
    s16x8 aw[8];
#pragma unroll
    for (int kc = 0; kc < 8; ++kc)
      aw[kc] = *(const s16x8*)(Wvb + (c0 + l15) * 256 + kc * 32 + g * 8);
#pragma unroll
    for (int pxt = 0; pxt < 4; ++pxt) {
      const int px = pxt * 16 + l15;
      f32x4 acc = *(const f32x4*)(bv + c0 + 4 * g);
#pragma unroll
      for (int kc = 0; kc < 8; ++kc) {
        s16x8 bxp = *(const s16x8*)(lds + px * 256 + (((kc * 4 + g) ^ (px & 31)) * 8));
        acc = mfma16(aw[kc], bxp, acc);
      }
#pragma unroll
      for (int j = 0; j < 4; ++j)
        Vo[((size_t)b * DIM + c0 + 4 * g + j) * HW + n0 + pxt * 16 + l15] = f2bf(acc[j]);
    }
  }
}

// ---------------- kernel 3: fused attention — 1 barrier/tile, counted vmcnt ----------------
// 512 threads = 8 waves, Q-tile 128, KV-tile 64 (attn3's verified tile math).
// Region r: barrier; stage K(r+2)->KB[r&1], V(r+2)->VB[(r+2)%3]; QK(r+1) rd KB[(r+1)&1]
//   wr PB[(r+1)&1]; PV(r) rd PB[r&1], VB[r%3]; vmcnt(4) lgkmcnt(0).
// vmcnt(4) leaves only this region's 4 V loads (FIFO retire) -> K lands in issue region,
// V by end of next. K dbuf / V 3-buf / P dbuf (16KB slots) alias-free.
// r9 BUGFIX: STAGE destinations are BYTE offsets -> must index ldsb (char*), not lds (u16*).
//   attn8/9/10 staged K into PB0 and V ~50KB off-target (u16-indexed byte offsets) -> NaN.
// LDS bytes: KB 0/8192 | PB 16384/32768 | lsum 49152 | VB 50176/82944/115712 | end 148480
__global__ __launch_bounds__(512, 1) void attn11(
    const u16* __restrict__ Qg, const u16* __restrict__ Kg, const u16* __restrict__ Vg,
    const float* __restrict__ qnsq, const u32* __restrict__ knmax_u,
    const float* __restrict__ sem, const float* __restrict__ gamma_p,
    float* __restrict__ out) {
  __shared__ u16 lds[74240];   // 148480 B
  char* ldsb = (char*)lds;
  const int t = threadIdx.x;
  const int b = blockIdx.x & 7;            // batch -> XCD (Q/K/V ~3MB L2-pinned)
  const int n0 = (blockIdx.x >> 3) << 7;   // *128
  const int w = t >> 6, lane = t & 63;
  const int l31 = lane & 31, g5 = lane >> 5;

  const u16* Qb = Qg + (size_t)b * HW * 64;
  const u16* Kb = Kg + (size_t)b * HW * 64;
  const u16* Vb = Vg + (size_t)b * DIM * HW;

  // ---- QK roles: wave (hh=w>>2, rr=w&3): keys hh*32, qrows rr*32 ----
  const int hh = w >> 2, rr = w & 3;
  const int key0 = hh * 32 + l31;
  const int qrow = rr * 32 + l31;
  int ka[4];
#pragma unroll
  for (int ks = 0; ks < 4; ++ks)
    ka[ks] = key0 * 128 + (((ks * 2 + g5) ^ (key0 & 7)) * 16);
  s16x8 qb[4];
#pragma unroll
  for (int ks = 0; ks < 4; ++ks)
    qb[ks] = *(const s16x8*)(Qb + (size_t)(n0 + qrow) * 64 + ks * 16 + g5 * 8);
  int pw_[4];
#pragma unroll
  for (int jg = 0; jg < 4; ++jg)
    pw_[jg] = qrow * 128 + (((hh * 4 + jg) ^ (qrow & 7)) * 16) + g5 * 8;
  const float mneg = -(sqrtf(qnsq[(size_t)b * HW + n0 + qrow] * __uint_as_float(knmax_u[b])) * 1.02f);

  // ---- PV roles: wave (rw=w>>2, cw=w&3): rows rw*64, channels cw*64 ----
  const int rw = w >> 2, cw = w & 3;
  int pa[2][4], va[2][4];
#pragma unroll
  for (int rt = 0; rt < 2; ++rt)
#pragma unroll
    for (int ks = 0; ks < 4; ++ks) {
      int r = rw * 64 + rt * 32 + l31;
      pa[rt][ks] = r * 128 + (((ks * 2 + g5) ^ (r & 7)) * 16);
    }
#pragma unroll
  for (int ct = 0; ct < 2; ++ct)
#pragma unroll
    for (int ks = 0; ks < 4; ++ks) {
      int c = cw * 64 + ct * 32 + l31;
      va[ct][ks] = 50176 + c * 128 + (((ks * 2 + g5) ^ (c & 7)) * 16);  // absolute bytes, VB0
    }

  f32x16 O[4] = {};
  float lreg = 0.f;

  // ---- staging: incremented pointers; linear LDS dest, inverse-swizzled global source ----
  const int srow = lane >> 3;
  const int sx = ((lane & 7) ^ srow) * 8;
  const u16* kp  = Kb + (size_t)(w * 8 + srow) * 64 + sx;
  const u16* vp0 = Vb + (size_t)((0 * 8 + w) * 8 + srow) * HW + sx;
  const u16* vp1 = Vb + (size_t)((1 * 8 + w) * 8 + srow) * HW + sx;
  const u16* vp2 = Vb + (size_t)((2 * 8 + w) * 8 + srow) * HW + sx;
  const u16* vp3 = Vb + (size_t)((3 * 8 + w) * 8 + srow) * HW + sx;

  auto STAGE_K = [&](int dstB) {   // dstB: BYTE offset; wave chunk = 1024 B
    gload_lds16(kp, (void*)(ldsb + dstB + w * 1024)); kp += 4096;
  };
  auto STAGE_V = [&](int dstB) {   // 4 chunks/wave, 1024 B each
    gload_lds16(vp0, (void*)(ldsb + dstB + (0 * 8 + w) * 1024)); vp0 += 64;
    gload_lds16(vp1, (void*)(ldsb + dstB + (1 * 8 + w) * 1024)); vp1 += 64;
    gload_lds16(vp2, (void*)(ldsb + dstB + (2 * 8 + w) * 1024)); vp2 += 64;
    gload_lds16(vp3, (void*)(ldsb + dstB + (3 * 8 + w) * 1024)); vp3 += 64;
  };

  auto do_qk = [&](auto KRC, auto PWC) {
    constexpr int KR = decltype(KRC)::value;
    constexpr int PW = decltype(PWC)::value;
    f32x16 sc;
#pragma unroll
    for (int r = 0; r < 16; ++r) sc[r] = mneg;   // fold -m^ into C-init
#pragma unroll
    for (int ks = 0; ks < 4; ++ks) {
      s16x8 kf = *(const s16x8*)(ldsb + KR + ka[ks]);
      sc = mfma32(kf, qb[ks], sc);
    }
#pragma unroll
    for (int jg = 0; jg < 4; ++jg) {
      float p0 = fexp2(sc[jg * 4 + 0]);
      float p1 = fexp2(sc[jg * 4 + 1]);
      float p2 = fexp2(sc[jg * 4 + 2]);
      float p3 = fexp2(sc[jg * 4 + 3]);
      lreg += (p0 + p1) + (p2 + p3);
      u32 w0 = cvtpk(p0, p1), w1 = cvtpk(p2, p3);
      u32x2 pk; pk[0] = w0; pk[1] = w1;
      *(u32x2*)(ldsb + PW + pw_[jg]) = pk;
    }
  };

  auto do_pv = [&](auto PRC) {
    constexpr int PR = decltype(PRC)::value;
    __builtin_amdgcn_s_setprio(1);
#pragma unroll
    for (int ks = 0; ks < 4; ++ks) {
      s16x8 ap0 = *(const s16x8*)(ldsb + PR + pa[0][ks]);
      s16x8 ap1 = *(const s16x8*)(ldsb + PR + pa[1][ks]);
      s16x8 vb0 = *(const s16x8*)(ldsb + va[0][ks]);
      s16x8 vb1 = *(const s16x8*)(ldsb + va[1][ks]);
      O[0] = mfma32(ap0, vb0, O[0]);
      O[1] = mfma32(ap0, vb1, O[1]);
      O[2] = mfma32(ap1, vb0, O[2]);
      O[3] = mfma32(ap1, vb1, O[3]);
    }
    __builtin_amdgcn_s_setprio(0);
  };

  // region r: barrier; stage K(r+2),V(r+2); QK(r+1); PV(r); vmcnt(4)+lgkmcnt(0)
  auto iter = [&](auto PARC, auto VBC, bool qk_next) {
    constexpr int PAR = decltype(PARC)::value;   // r & 1
    constexpr int VB  = decltype(VBC)::value;    // r % 3
    __builtin_amdgcn_s_barrier();
    __builtin_amdgcn_sched_barrier(0);
    STAGE_K(PAR * 8192);                               // K(r+2) -> KB[r&1]
    STAGE_V(50176 + ((VB + 2) % 3) * 32768);           // V(r+2) -> VB[(r+2)%3]
    if (qk_next)
      do_qk(ic<(PAR ^ 1) * 8192>{}, ic<16384 + (PAR ^ 1) * 16384>{});   // QK(r+1)
    do_pv(ic<16384 + PAR * 16384>{});                  // PV(r): PB[r&1], VB[r%3] via va
    // rotate V read addresses to next buffer
    constexpr int D = (VB == 2) ? -65536 : 32768;
#pragma unroll
    for (int ct = 0; ct < 2; ++ct)
#pragma unroll
      for (int ks = 0; ks < 4; ++ks) va[ct][ks] += D;
    asm volatile("s_waitcnt vmcnt(4) lgkmcnt(0)" ::: "memory");  // K(r+2), V(r+1) landed; P published
  };

  // ---- prologue: stage K(0),V(0),K(1),V(1); publish; QK(0) ----
  STAGE_K(0);
  STAGE_V(50176);
  STAGE_K(8192);
  STAGE_V(50176 + 32768);
  asm volatile("s_waitcnt vmcnt(4)" ::: "memory");   // K(0),V(0),K(1) landed; V(1) in flight
  __builtin_amdgcn_s_barrier();
  __builtin_amdgcn_sched_barrier(0);
  do_qk(ic<0>{}, ic<16384>{});                        // P(0) -> PB0
  asm volatile("s_waitcnt lgkmcnt(0)" ::: "memory");

  for (int kt = 0; kt < 60; kt += 6) {
    iter(ic<0>{}, ic<0>{}, true);
    iter(ic<1>{}, ic<1>{}, true);
    iter(ic<0>{}, ic<2>{}, true);
    iter(ic<1>{}, ic<0>{}, true);
    iter(ic<0>{}, ic<1>{}, true);
    iter(ic<1>{}, ic<2>{}, true);
  }
  iter(ic<0>{}, ic<0>{}, true);    // r=60
  iter(ic<1>{}, ic<1>{}, true);    // r=61
  iter(ic<0>{}, ic<2>{}, true);    // r=62 (stages tile 64: benign, lands unread in-ws)
  iter(ic<1>{}, ic<0>{}, false);   // r=63 (stages tile 65: benign)

  // ---- merge l across (g5, hh) then epilogue ----
  float* lfp = (float*)(ldsb + 49152);
  float ls = lreg + __shfl_xor(lreg, 32);
  if (lane < 32) lfp[hh * 128 + qrow] = ls;
  __syncthreads();
  const float gm = gamma_p[0];
#pragma unroll
  for (int rt = 0; rt < 2; ++rt) {
#pragma unroll
    for (int jg = 0; jg < 4; ++jg) {
      const int noff = rw * 64 + rt * 32 + jg * 8 + 4 * g5;
      f32x4 l0 = *(const f32x4*)(lfp + noff);
      f32x4 l1 = *(const f32x4*)(lfp + 128 + noff);
      f32x4 inv;
#pragma unroll
      for (int j = 0; j < 4; ++j) inv[j] = __builtin_amdgcn_rcpf(l0[j] + l1[j]);
#pragma unroll
      for (int ct = 0; ct < 2; ++ct) {
        const int c = cw * 64 + ct * 32 + l31;
        size_t base = ((size_t)b * DIM + c) * HW + n0 + noff;
        f32x4 sv = *(const f32x4*)(sem + base);
        f32x4 ov;
#pragma unroll
        for (int j = 0; j < 4; ++j)
          ov[j] = sv[j] + gm * (O[rt * 2 + ct][jg * 4 + j] * inv[j]);
        *(f32x4*)(out + base) = ov;
      }
    }
  }
}

extern "C" void kernel_launch(void* const* d_in, const int* in_sizes, int n_in,
                              void* d_out, int out_size, void* d_ws, size_t ws_size,
                              hipStream_t stream) {
  const float* sem   = (const float*)d_in[0];
  const float* foren = (const float*)d_in[1];
  const float* Wq    = (const float*)d_in[2];
  const float* bq    = (const float*)d_in[3];
  const float* Wk    = (const float*)d_in[4];
  const float* bk    = (const float*)d_in[5];
  const float* Wv    = (const float*)d_in[6];
  const float* bv    = (const float*)d_in[7];
  const float* gamma = (const float*)d_in[8];
  float* out = (float*)d_out;

  // ws (u16 units): Wq 16K | Wk 16K | Wv 64K | Q 2M | K 2M | V 8M | qnsq f32 32K | knmax u32 8
  u16* Wqb = (u16*)d_ws;
  u16* Wkb = Wqb + 16384;
  u16* Wvb = Wkb + 16384;
  u16* Q   = Wvb + 65536;
  u16* K   = Q + (size_t)NB * HW * 64;
  u16* V   = K + (size_t)NB * HW * 64;
  float* qnsq = (float*)(V + (size_t)NB * DIM * HW);
  u32* knmax_u = (u32*)(qnsq + (size_t)NB * HW);

  prep_w  <<<384, 256, 0, stream>>>(Wq, Wk, Wv, Wqb, knmax_u);
  proj_all<<<1024, 256, 0, stream>>>(sem, foren, Wqb, Wkb, Wvb, bq, bk, bv, Q, K, V, qnsq, knmax_u);
  attn11  <<<256, 512, 0, stream>>>(Q, K, V, qnsq, knmax_u, sem, gamma, out);
}